// Round 3
// baseline (323.838 us; speedup 1.0000x reference)
//
#include <hip/hip_runtime.h>

#define S_LEN 2048
#define DIM 2048
#define NH 16
#define HD 128
#define WIN 512
#define QKVD (3 * DIM)  // 6144

typedef unsigned short u16;
typedef __bf16 bf16x8 __attribute__((ext_vector_type(8)));
typedef float f32x4 __attribute__((ext_vector_type(4)));

__device__ __forceinline__ u16 f2bf(float f) {
  unsigned u = __builtin_bit_cast(unsigned, f);
  u += 0x7FFFu + ((u >> 16) & 1u);
  return (u16)(u >> 16);
}
__device__ __forceinline__ float bf2f(u16 b) {
  return __builtin_bit_cast(float, (unsigned)b << 16);
}
__device__ __forceinline__ void async16(const void* g, void* l) {
  __builtin_amdgcn_global_load_lds((__attribute__((address_space(1))) void*)g,
                                   (__attribute__((address_space(3))) void*)l,
                                   16, 0, 0);
}

// ---------------- fp32 -> bf16 convert (vectorized) ----------------
__global__ __launch_bounds__(256) void cvt_kernel(const float* __restrict__ in,
                                                  u16* __restrict__ out, int n) {
  int i = (blockIdx.x * 256 + threadIdx.x) * 4;
  if (i < n) {
    float4 v = *(const float4*)(in + i);
    ushort4 o;
    o.x = f2bf(v.x); o.y = f2bf(v.y); o.z = f2bf(v.z); o.w = f2bf(v.w);
    *(ushort4*)(out + i) = o;
  }
}

// ---------------- RoPE cos/sin table (double precision) ----------------
__global__ __launch_bounds__(256) void rope_tab_kernel(float* __restrict__ cosT,
                                                       float* __restrict__ sinT) {
  int idx = blockIdx.x * 256 + threadIdx.x;  // S*64 entries
  int s = idx >> 6, j = idx & 63;
  double freq = exp((double)j * -0.14391156831212787);  // -ln(10000)/64
  double a = (double)s * freq;
  cosT[idx] = (float)cos(a);
  sinT[idx] = (float)sin(a);
}

// ---------------- GEMM C = A * B^T  (both row-major, K contiguous) ------
// 128x128 tile, BK=64, 4 waves, m97 structure (global_load_lds width 16).
template <typename TO>
__global__ __launch_bounds__(256, 2) void gemm_bt(const u16* __restrict__ A,
                                                  const u16* __restrict__ B,
                                                  TO* __restrict__ C,
                                                  int M, int N, int K) {
  __shared__ __align__(16) u16 As[128 * 64];
  __shared__ __align__(16) u16 Bs[128 * 64];
  const int tiles_n = N >> 7;
  const int m0 = (blockIdx.x / tiles_n) << 7;
  const int n0 = (blockIdx.x % tiles_n) << 7;
  const int t = threadIdx.x;
  const int l = t & 63, w = t >> 6;
  const int wr = w >> 1, wc = w & 1;
  const int l16 = l & 15, lg = l >> 4;
  f32x4 acc[4][4] = {};
  for (int k0 = 0; k0 < K; k0 += 64) {
    __syncthreads();
#pragma unroll
    for (int i = 0; i < 4; ++i) {
      int c = t + (i << 8);
      int r = c >> 3, cc = c & 7;
      async16(A + (size_t)(m0 + r) * K + k0 + cc * 8, (char*)As + c * 16);
    }
#pragma unroll
    for (int i = 0; i < 4; ++i) {
      int c = t + (i << 8);
      int r = c >> 3, cc = c & 7;
      async16(B + (size_t)(n0 + r) * K + k0 + cc * 8, (char*)Bs + c * 16);
    }
    __syncthreads();
#pragma unroll
    for (int ks = 0; ks < 2; ++ks) {
      bf16x8 af[4], bfv[4];
#pragma unroll
      for (int m = 0; m < 4; ++m)
        af[m] = *(const bf16x8*)(As + (wr * 64 + m * 16 + l16) * 64 + ks * 32 + lg * 8);
#pragma unroll
      for (int n = 0; n < 4; ++n)
        bfv[n] = *(const bf16x8*)(Bs + (wc * 64 + n * 16 + l16) * 64 + ks * 32 + lg * 8);
#pragma unroll
      for (int m = 0; m < 4; ++m)
#pragma unroll
        for (int n = 0; n < 4; ++n)
          acc[m][n] = __builtin_amdgcn_mfma_f32_16x16x32_bf16(af[m], bfv[n], acc[m][n], 0, 0, 0);
    }
  }
  const int rb = m0 + wr * 64 + lg * 4;
  const int cb = n0 + wc * 64 + l16;
#pragma unroll
  for (int m = 0; m < 4; ++m)
#pragma unroll
    for (int n = 0; n < 4; ++n)
#pragma unroll
      for (int r = 0; r < 4; ++r) {
        float v = acc[m][n][r];
        size_t idx = (size_t)(rb + m * 16 + r) * N + cb + n * 16;
        if constexpr (sizeof(TO) == 2) C[idx] = f2bf(v);
        else C[idx] = v;
      }
}

// ---------------- RoPE applied IN-PLACE on qkv (B,S,3D) bf16 ----------------
// One block per (b,s) row; each thread owns whole (d, d+64) pairs -> race-free.
__global__ __launch_bounds__(256) void rope_kernel(u16* __restrict__ qkv,
                                                   const float* __restrict__ cosT,
                                                   const float* __restrict__ sinT) {
  const int row = blockIdx.x;  // b*S + s
  const int s = row & (S_LEN - 1);
  const int t = threadIdx.x;
  u16* base = qkv + (size_t)row * QKVD;
#pragma unroll
  for (int j = 0; j < 4; ++j) {
    const int pi = t + j * 256;  // 0..1023 : 16 heads x 64 pairs
    const int h = pi >> 6, d = pi & 63;
    const float c = cosT[(s << 6) + d];
    const float sn = sinT[(s << 6) + d];
    u16* q = base + h * HD;
    float q1 = bf2f(q[d]), q2 = bf2f(q[d + 64]);
    q[d] = f2bf(q1 * c - q2 * sn);
    q[d + 64] = f2bf(q2 * c + q1 * sn);
    u16* k = base + DIM + h * HD;
    float k1 = bf2f(k[d]), k2 = bf2f(k[d + 64]);
    k[d] = f2bf(k1 * c - k2 * sn);
    k[d + 64] = f2bf(k2 * c + k1 * sn);
  }
}

// ---------------- sliding-window flash attention ----------------
// grid = (B*H) * (S/64); 4 waves x 16 q-rows; KVBLK=64.
// Q/K/V read directly from the (B,S,3D) qkv buffer (row stride QKVD).
__global__ __launch_bounds__(256, 2) void attn_kernel(const u16* __restrict__ qkv,
                                                      u16* __restrict__ attnO) {
  const int bid = blockIdx.x;
  const int qt = bid & 31;
  const int bh = bid >> 5;
  const int q0 = qt << 6;
  const int b = bh >> 4, h = bh & 15;
  const u16* Qp = qkv + (size_t)b * S_LEN * QKVD + h * HD;  // + s*QKVD per row
  const u16* Kp = Qp + DIM;
  const u16* Vp = Qp + 2 * DIM;
  __shared__ __align__(16) char Ks[64 * 256];      // XOR-swizzled [64][128] bf16
  __shared__ __align__(16) u16 Vt[128][72];        // transposed V, padded
  __shared__ __align__(16) __bf16 Ps[4][16 * 72];  // per-wave P, padded (bf16-typed)
  const int t = threadIdx.x;
  const int w = t >> 6, l = t & 63;
  const int l16 = l & 15, lg = l >> 4;
  // Q fragments hoisted (wave w owns q rows q0+w*16 .. +15)
  bf16x8 qf[4];
  {
    const u16* qrow = Qp + (size_t)(q0 + w * 16 + l16) * QKVD;
#pragma unroll
    for (int ks = 0; ks < 4; ++ks) qf[ks] = *(const bf16x8*)(qrow + ks * 32 + lg * 8);
  }
  f32x4 oacc[8] = {};
  float mrow[4], lrow[4];
#pragma unroll
  for (int r = 0; r < 4; ++r) { mrow[r] = -1e30f; lrow[r] = 0.f; }
  const int t_lo = max(0, qt - 8);
  for (int kt = t_lo; kt <= qt; ++kt) {
    const int kv0 = kt << 6;
    __syncthreads();
    // stage K with source-pre-swizzled global_load_lds (read-side XOR matches)
#pragma unroll
    for (int i = 0; i < 4; ++i) {
      int c = t + (i << 8);
      int row = c >> 4, ch = c & 15;
      int sch = ch ^ (row & 7);
      async16(Kp + (size_t)(kv0 + row) * QKVD + sch * 8, Ks + c * 16);
    }
    // stage V transposed (reg -> ds_write_b16): 64 rows x 16 chunks = 1024 chunks
#pragma unroll
    for (int i = 0; i < 4; ++i) {
      int c = t + (i << 8);                 // 0..1023
      int row = c >> 4, c8 = c & 15;        // row in [0,64), chunk in [0,16)
      const uint4 dv = *(const uint4*)(Vp + (size_t)(kv0 + row) * QKVD + c8 * 8);
      unsigned vv[4] = {dv.x, dv.y, dv.z, dv.w};
#pragma unroll
      for (int j2 = 0; j2 < 4; ++j2) {
        Vt[c8 * 8 + j2 * 2][row] = (u16)(vv[j2] & 0xffffu);
        Vt[c8 * 8 + j2 * 2 + 1][row] = (u16)(vv[j2] >> 16);
      }
    }
    __syncthreads();
    // QK^T : 16x64 strip per wave
    f32x4 sc[4];
#pragma unroll
    for (int c4 = 0; c4 < 4; ++c4) {
      f32x4 sa = {};
#pragma unroll
      for (int ks = 0; ks < 4; ++ks) {
        const int krow = c4 * 16 + l16;
        const int ch = (ks * 4 + lg) ^ (krow & 7);
        bf16x8 kf = *(const bf16x8*)(Ks + krow * 256 + ch * 16);
        sa = __builtin_amdgcn_mfma_f32_16x16x32_bf16(qf[ks], kf, sa, 0, 0, 0);
      }
      sc[c4] = sa;
    }
    const float scale = 0.08838834764831843f;  // 1/sqrt(128)
    const int qi_base = q0 + w * 16 + lg * 4;
    float pm[4];
#pragma unroll
    for (int r = 0; r < 4; ++r) pm[r] = -1e30f;
#pragma unroll
    for (int c4 = 0; c4 < 4; ++c4) {
      const int kj = kv0 + c4 * 16 + l16;
#pragma unroll
      for (int r = 0; r < 4; ++r) {
        const int diff = qi_base + r - kj;
        float v = sc[c4][r] * scale;
        v = (diff >= 0 && diff < WIN) ? v : -1e30f;
        sc[c4][r] = v;
        pm[r] = fmaxf(pm[r], v);
      }
    }
#pragma unroll
    for (int off = 1; off < 16; off <<= 1)
#pragma unroll
      for (int r = 0; r < 4; ++r) pm[r] = fmaxf(pm[r], __shfl_xor(pm[r], off));
    float scl[4];
#pragma unroll
    for (int r = 0; r < 4; ++r) {
      float mn = fmaxf(mrow[r], pm[r]);
      scl[r] = expf(mrow[r] - mn);
      mrow[r] = mn;
    }
    __bf16* pp = Ps[w];
    float ps[4] = {0.f, 0.f, 0.f, 0.f};
#pragma unroll
    for (int c4 = 0; c4 < 4; ++c4)
#pragma unroll
      for (int r = 0; r < 4; ++r) {
        float p = expf(sc[c4][r] - mrow[r]);
        ps[r] += p;
        pp[(lg * 4 + r) * 72 + c4 * 16 + l16] = (__bf16)p;  // bf16-typed store
      }
#pragma unroll
    for (int off = 1; off < 16; off <<= 1)
#pragma unroll
      for (int r = 0; r < 4; ++r) ps[r] += __shfl_xor(ps[r], off);
#pragma unroll
    for (int r = 0; r < 4; ++r) lrow[r] = lrow[r] * scl[r] + ps[r];
#pragma unroll
    for (int dt = 0; dt < 8; ++dt) {
      f32x4 o = oacc[dt];
#pragma unroll
      for (int r = 0; r < 4; ++r) o[r] *= scl[r];
      oacc[dt] = o;
    }
    // compiler memory fence: P stores must not be reordered past the P loads
    asm volatile("" ::: "memory");
    // PV: out += P * V   (Vt rows = d, K-contig in kv)
#pragma unroll
    for (int ks = 0; ks < 2; ++ks) {
      bf16x8 pf = *(const bf16x8*)(pp + l16 * 72 + ks * 32 + lg * 8);
#pragma unroll
      for (int dt = 0; dt < 8; ++dt) {
        bf16x8 vf = *(const bf16x8*)(&Vt[dt * 16 + l16][ks * 32 + lg * 8]);
        oacc[dt] = __builtin_amdgcn_mfma_f32_16x16x32_bf16(pf, vf, oacc[dt], 0, 0, 0);
      }
    }
  }
  // epilogue: normalize and store bf16 into (B,S,D) layout
  const int qi = q0 + w * 16 + lg * 4;
  u16* orow = attnO + ((size_t)(b * S_LEN + qi) * DIM) + h * HD;
#pragma unroll
  for (int r = 0; r < 4; ++r) {
    float inv = 1.f / lrow[r];
#pragma unroll
    for (int dt = 0; dt < 8; ++dt)
      orow[(size_t)r * DIM + dt * 16 + l16] = f2bf(oacc[dt][r] * inv);
  }
}

extern "C" void kernel_launch(void* const* d_in, const int* in_sizes, int n_in,
                              void* d_out, int out_size, void* d_ws, size_t ws_size,
                              hipStream_t stream) {
  const float* x = (const float*)d_in[0];
  const float* w_qkv = (const float*)d_in[1];
  const float* w_out = (const float*)d_in[2];
  float* out = (float*)d_out;

  char* ws = (char*)d_ws;
  size_t off = 0;
  auto alloc = [&](size_t bytes) {
    void* p = ws + off;
    off = (off + bytes + 255) & ~(size_t)255;
    return p;
  };
  const size_t rows = 2ull * S_LEN;                // 4096
  u16* wqkvb = (u16*)alloc(3ull * DIM * DIM * 2);  // 25.2 MB (reused as attn out)
  u16* woutb = (u16*)alloc((size_t)DIM * DIM * 2); // 8.4 MB
  u16* xb    = (u16*)alloc(rows * DIM * 2);        // 16.8 MB
  u16* qkvb  = (u16*)alloc(rows * 3 * DIM * 2);    // 50.3 MB
  float* cosT = (float*)alloc((size_t)S_LEN * 64 * 4);
  float* sinT = (float*)alloc((size_t)S_LEN * 64 * 4);
  // total ~102 MB

  // converts
  cvt_kernel<<<(3 * DIM * DIM) / 1024, 256, 0, stream>>>(w_qkv, wqkvb, 3 * DIM * DIM);
  cvt_kernel<<<(DIM * DIM) / 1024, 256, 0, stream>>>(w_out, woutb, DIM * DIM);
  cvt_kernel<<<(int)(rows * DIM / 1024), 256, 0, stream>>>(x, xb, (int)(rows * DIM));
  rope_tab_kernel<<<(S_LEN * 64) / 256, 256, 0, stream>>>(cosT, sinT);
  // QKV projection: (4096 x 2048) * (6144 x 2048)^T -> bf16
  gemm_bt<u16><<<(int)(rows / 128) * (3 * DIM / 128), 256, 0, stream>>>(
      xb, wqkvb, qkvb, (int)rows, 3 * DIM, DIM);
  // RoPE in-place on q,k parts of qkv
  rope_kernel<<<(int)rows, 256, 0, stream>>>(qkvb, cosT, sinT);
  // attention reads qkv directly; writes bf16 into wqkvb region (free now)
  u16* attnb = wqkvb;
  attn_kernel<<<2 * NH * (S_LEN / 64), 256, 0, stream>>>(qkvb, attnb);
  // output projection -> fp32 d_out
  gemm_bt<float><<<(int)(rows / 128) * (DIM / 128), 256, 0, stream>>>(
      attnb, woutb, out, (int)rows, DIM, DIM);
}